// Round 1
// baseline (325.810 us; speedup 1.0000x reference)
//
#include <hip/hip_runtime.h>
#include <stdint.h>

// MFMA fragment types (gfx950: v8bf16 inputs, v4f32 acc — LLVM signature)
typedef __bf16 bf16x8 __attribute__((ext_vector_type(8)));
typedef float  f32x4  __attribute__((ext_vector_type(4)));

__device__ __forceinline__ uint32_t pack_bf16x2(float a, float b) {
    // round-to-nearest-even fp32 -> bf16, packed low/high
    uint32_t ua = __builtin_bit_cast(uint32_t, a);
    uint32_t ub = __builtin_bit_cast(uint32_t, b);
    ua = (ua + 0x7FFFu + ((ua >> 16) & 1u)) >> 16;
    ub = (ub + 0x7FFFu + ((ub >> 16) & 1u)) >> 16;
    return ua | (ub << 16);
}

// One block: batch b, output channels [o0, o0+32).
// GEMM: rows 0..31 = W1[o,:]·x  (Y1), rows 32..63 = W2[o,:]·x (Y2), N = L = 512, K = C = 256.
// Then y = Y1 + gather_cols(Y2, idx) (bias cancels in InstanceNorm), norm over L, ReLU.
__global__ __launch_bounds__(256, 2)
void edgeconv_fused(const float* __restrict__ x,
                    const int*   __restrict__ idx,
                    const float* __restrict__ W,
                    float*       __restrict__ out)
{
    // LDS plan (exactly 64 KiB):
    //   [0,32K)  a_lds : W tile bf16, 32 slabs of (64 rows x 8 k)  -> aligned b128 frag reads
    //   [32K,64K) xT   : x chunk bf16, 4 slabs of (512 l x 8 k)    -> aligned b128 frag reads
    //   After GEMM (barrier-separated aliases):
    //   [0,64K)  y2    : fp32 [32][512] for the column gather
    //   [0,1K)   red   : fp32 [32 rows][4 waves][2] partial sums (after gather done)
    __shared__ __align__(16) unsigned char smem[65536];
    unsigned short* a_lds = (unsigned short*)smem;
    unsigned short* xT    = (unsigned short*)(smem + 32768);
    float* y2             = (float*)smem;
    float* red            = (float*)smem;

    const int tid  = threadIdx.x;
    const int wv   = tid >> 6;      // wave 0..3 -> cols [wv*128, wv*128+128)
    const int lane = tid & 63;
    const int m    = lane & 15;     // A-frag row / B-frag col / D col
    const int q    = lane >> 4;     // quad: k-slice for A/B, row-group for D

    // XCD-locality swizzle: the 8 o-blocks of one b are 8 apart in id (same XCD
    // under round-robin id%8), within a 64-id window -> x[b] stays in that XCD's L2.
    const int id  = blockIdx.x;
    const int rem = id & 63;
    const int b   = ((id >> 6) << 3) + (rem & 7);
    const int o0  = (rem >> 3) << 5;

    // ---- stage W tile (64 rows x 256 k) -> bf16 slabs (once) ----
    // row r<32: W[o0+r][k] (W1);  r>=32: W[o0+r-32][256+k] (W2)
    for (int g = 0; g < 16; ++g) {
        int gid = (g << 8) + tid;       // 0..4095 (row, float4-group)
        int r   = gid >> 6;             // 0..63
        int kg4 = gid & 63;             // float4 index in row
        const float4* src = (const float4*)(W + ((size_t)(o0 + (r & 31)) << 9)
                                              + ((r >> 5) << 8) + (kg4 << 2));
        float4 f = *src;                 // coalesced 16B loads
        int k0  = kg4 << 2;
        int off = ((k0 >> 3) << 9) + (r << 3) + (k0 & 7);  // slab*512 + r*8 + (k&7)
        uint2 u; u.x = pack_bf16x2(f.x, f.y); u.y = pack_bf16x2(f.z, f.w);
        *(uint2*)(a_lds + off) = u;
    }

    f32x4 acc[4][8];
    #pragma unroll
    for (int mt = 0; mt < 4; ++mt)
        #pragma unroll
        for (int nt = 0; nt < 8; ++nt)
            acc[mt][nt] = (f32x4){0.f, 0.f, 0.f, 0.f};

    const float* xb = x + ((size_t)b << 17);   // b * C * L

    // ---- K loop: 8 chunks of 32 k ----
    for (int kc = 0; kc < 8; ++kc) {
        __syncthreads();                        // prev chunk's reads done (also fences W stage at kc=0... see below)
        // stage x[kc*32 .. +32][0..512) transposed into xT slabs
        #pragma unroll
        for (int g = 0; g < 8; ++g) {
            int gid = (g << 8) + tid;           // 0..2047
            int l   = gid & 511;
            int kg  = gid >> 9;                 // 0..3 (8 k's each)
            int kb  = (kc << 5) + (kg << 3);
            const float* xp = xb + ((size_t)kb << 9) + l;   // coalesced dword loads per j
            uint4 u;
            u.x = pack_bf16x2(xp[0],    xp[512]);
            u.y = pack_bf16x2(xp[1024], xp[1536]);
            u.z = pack_bf16x2(xp[2048], xp[2560]);
            u.w = pack_bf16x2(xp[3072], xp[3584]);
            *(uint4*)(xT + (kg << 12) + (l << 3)) = u;      // aligned b128, bank-balanced
        }
        __syncthreads();

        bf16x8 av[4], bv[8];
        const unsigned short* abase = a_lds + (((kc << 2) + q) << 9) + (m << 3);
        #pragma unroll
        for (int mt = 0; mt < 4; ++mt)
            av[mt] = *(const bf16x8*)(abase + (mt << 7));   // A[m = mt*16+m][k = kc*32+q*8+j]
        const unsigned short* bbase = xT + (q << 12) + (((wv << 7) + m) << 3);
        #pragma unroll
        for (int nt = 0; nt < 8; ++nt)
            bv[nt] = *(const bf16x8*)(bbase + (nt << 7));   // B[k = q*8+j][n = wv*128+nt*16+m]

        #pragma unroll
        for (int mt = 0; mt < 4; ++mt)
            #pragma unroll
            for (int nt = 0; nt < 8; ++nt)
                acc[mt][nt] = __builtin_amdgcn_mfma_f32_16x16x32_bf16(av[mt], bv[nt], acc[mt][nt], 0, 0, 0);
    }

    __syncthreads();   // all a_lds/xT reads done -> safe to alias with y2

    // ---- Y2 (rows 32..63) -> LDS fp32 [32][512] ----
    #pragma unroll
    for (int mt = 2; mt < 4; ++mt)
        #pragma unroll
        for (int nt = 0; nt < 8; ++nt)
            #pragma unroll
            for (int r4 = 0; r4 < 4; ++r4) {
                int r   = ((mt - 2) << 4) + (q << 2) + r4;  // D row = quad*4+reg (+16 per mt)
                int col = (wv << 7) + (nt << 4) + m;        // D col = lane&15
                y2[(r << 9) + col] = acc[mt][nt][r4];
            }
    __syncthreads();

    // ---- gather + per-row partial sums (in registers) ----
    int iv[8];
    #pragma unroll
    for (int nt = 0; nt < 8; ++nt)
        iv[nt] = idx[((size_t)b << 9) + (wv << 7) + (nt << 4) + m];

    float v[2][8][4];
    float s_[2][4], q_[2][4];
    #pragma unroll
    for (int mt = 0; mt < 2; ++mt)
        #pragma unroll
        for (int r4 = 0; r4 < 4; ++r4) { s_[mt][r4] = 0.f; q_[mt][r4] = 0.f; }

    #pragma unroll
    for (int mt = 0; mt < 2; ++mt)
        #pragma unroll
        for (int nt = 0; nt < 8; ++nt)
            #pragma unroll
            for (int r4 = 0; r4 < 4; ++r4) {
                int r = (mt << 4) + (q << 2) + r4;          // Y1 row == Y2 row (same o)
                float gth = (iv[nt] < 512) ? y2[(r << 9) + iv[nt]] : 0.f;  // idx==512 -> pad col (zero)
                float val = acc[mt][nt][r4] + gth;
                v[mt][nt][r4] = val;
                s_[mt][r4] += val;
                q_[mt][r4] += val * val;
            }

    __syncthreads();   // all y2 reads complete before red aliases it

    // ---- reduce: 8 in-lane + 16-lane quad butterfly + cross-wave via LDS ----
    #pragma unroll
    for (int mt = 0; mt < 2; ++mt)
        #pragma unroll
        for (int r4 = 0; r4 < 4; ++r4) {
            float s = s_[mt][r4], ss = q_[mt][r4];
            #pragma unroll
            for (int off = 1; off < 16; off <<= 1) {
                s  += __shfl_xor(s,  off, 64);
                ss += __shfl_xor(ss, off, 64);
            }
            if (m == 0) {
                int r = (mt << 4) + (q << 2) + r4;
                red[(r << 3) + (wv << 1)]     = s;
                red[(r << 3) + (wv << 1) + 1] = ss;
            }
        }
    __syncthreads();

    // ---- finalize: mean, biased var, rsqrt, relu, coalesced store ----
    #pragma unroll
    for (int mt = 0; mt < 2; ++mt)
        #pragma unroll
        for (int r4 = 0; r4 < 4; ++r4) {
            int r = (mt << 4) + (q << 2) + r4;
            float S = red[(r << 3)]     + red[(r << 3) + 2] + red[(r << 3) + 4] + red[(r << 3) + 6];
            float Q = red[(r << 3) + 1] + red[(r << 3) + 3] + red[(r << 3) + 5] + red[(r << 3) + 7];
            float mu  = S * (1.0f / 512.0f);
            float var = Q * (1.0f / 512.0f) - mu * mu;      // biased, matches jnp.mean
            float rs  = rsqrtf(var + 1e-5f);
            float* op = out + (((size_t)(b << 8) + o0 + r) << 9) + (wv << 7) + m;
            #pragma unroll
            for (int nt = 0; nt < 8; ++nt) {
                float t = (v[mt][nt][r4] - mu) * rs;
                op[nt << 4] = fmaxf(t, 0.0f);
            }
        }
}

extern "C" void kernel_launch(void* const* d_in, const int* in_sizes, int n_in,
                              void* d_out, int out_size, void* d_ws, size_t ws_size,
                              hipStream_t stream) {
    const float* x   = (const float*)d_in[0];   // [256,256,512] fp32
    const int*   idx = (const int*)  d_in[1];   // [256,512] int32, 512 == pad
    const float* W   = (const float*)d_in[2];   // [256,512] fp32
    // d_in[3] (bias) intentionally unused: constant-over-L shift cancels in InstanceNorm.
    float* out = (float*)d_out;                 // [256,256,512] fp32

    edgeconv_fused<<<dim3(2048), dim3(256), 0, stream>>>(x, idx, W, out);
}

// Round 2
// 317.219 us; speedup vs baseline: 1.0271x; 1.0271x over previous
//
#include <hip/hip_runtime.h>
#include <hip/hip_bf16.h>
#include <stdint.h>

typedef __bf16 bf16x8 __attribute__((ext_vector_type(8)));
typedef float  f32x4  __attribute__((ext_vector_type(4)));

// packed fp32x2 -> bf16x2 (RNE) -- lowers to v_cvt_pk_bf16_f32 on gfx950
__device__ __forceinline__ uint32_t cvt2(float a, float b) {
    __hip_bfloat162 h = __float22bfloat162_rn(make_float2(a, b));
    uint32_t u; __builtin_memcpy(&u, &h, 4); return u;
}
__device__ __forceinline__ float bflo(uint32_t u) { uint32_t t = u << 16;         float f; __builtin_memcpy(&f, &t, 4); return f; }
__device__ __forceinline__ float bfhi(uint32_t u) { uint32_t t = u & 0xffff0000u; float f; __builtin_memcpy(&f, &t, 4); return f; }
// 16B-unit XOR swizzle: balances LDS banks for both staging stores and frag reads
__device__ __forceinline__ int swz(int u) { return u ^ ((u >> 3) & 7); }

// One block: batch b, output channels [o0, o0+32).
// GEMM rows 0..31 = W1[o,:]*x (Y1), rows 32..63 = W2[o,:]*x (Y2); N=L=512, K=C=256.
// y = Y1 + gather_cols(Y2, idx); bias cancels in InstanceNorm; norm over L; ReLU.
__global__ __launch_bounds__(256, 2)
void edgeconv_fused(const float* __restrict__ x,
                    const int*   __restrict__ idx,
                    const float* __restrict__ W,
                    float*       __restrict__ out)
{
    // LDS (64 KiB):
    //  GEMM phase:  [0,32K) wlds: W bf16 [32 slabs][64 units][8k], unit idx = swz(r)^(slab&7)
    //               [32K,64K) xT: x chunk bf16 [4 slabs][512 units][8k], unit idx = swz(l)
    //  Epilogue (barrier-separated aliases):
    //               [0,36864) y2: bf16 [512 col][36] (rows 0..31 used; stride 36 -> 8B align + bank spread)
    //               [38912,39936) red: fp32 [32 rows][4 waves][2]
    __shared__ __align__(16) unsigned char smem[65536];
    unsigned short* wlds = (unsigned short*)smem;
    unsigned short* xT   = (unsigned short*)(smem + 32768);
    unsigned short* y2   = (unsigned short*)smem;
    float*          red  = (float*)(smem + 38912);

    const int tid  = threadIdx.x;
    const int wv   = tid >> 6;      // wave -> cols [wv*128, wv*128+128)
    const int lane = tid & 63;
    const int m    = lane & 15;     // frag row/col index
    const int q    = lane >> 4;     // quad

    // XCD swizzle: the 8 o-blocks of one b are 8 ids apart -> same XCD under round-robin
    const int id  = blockIdx.x;
    const int rem = id & 63;
    const int b   = ((id >> 6) << 3) + (rem & 7);
    const int o0  = (rem >> 3) << 5;

    const float* xb = x + ((size_t)b << 17);   // b * C * L

    // ---- stage W once: iter i -> row r = i*4+wv (wave-uniform), k = lane*4 (coalesced 1KB/row) ----
    #pragma unroll
    for (int i = 0; i < 16; ++i) {
        int r = (i << 2) + wv;                  // 0..63 ; r<32: W1 row, r>=32: W2 row
        const float4 f = *(const float4*)(W + ((size_t)(o0 + (r & 31)) << 9)
                                            + ((r >> 5) << 8) + (lane << 2));
        uint2 p; p.x = cvt2(f.x, f.y); p.y = cvt2(f.z, f.w);
        int sl = lane >> 1;                     // global k-octet 0..31
        *(uint2*)(wlds + (sl << 9) + ((swz(r) ^ (sl & 7)) << 3) + ((lane & 1) << 2)) = p;
    }

    f32x4 acc[4][8];
    #pragma unroll
    for (int mt = 0; mt < 4; ++mt)
        #pragma unroll
        for (int nt = 0; nt < 8; ++nt)
            acc[mt][nt] = (f32x4){0.f, 0.f, 0.f, 0.f};

    // x staging: thread (g,tid) covers slab s2 = (g*256+tid)>>7, l4 = (g*256+tid)&127.
    // loads: 8 x dwordx4 (k = kc*32+s2*8+j, l = 4*l4..4*l4+3), coalesced 1KB per instr.
    float4 xr0[8], xr1[8];
    auto loadg = [&](int kc, int g, float4* xr) {
        int gid = (g << 8) + tid;
        int s2  = gid >> 7;
        int l4  = gid & 127;
        const float* base = xb + ((size_t)((kc << 5) + (s2 << 3)) << 9) + (l4 << 2);
        #pragma unroll
        for (int j = 0; j < 8; ++j) xr[j] = *(const float4*)(base + (j << 9));
    };
    auto storeg = [&](int g, const float4* xr) {
        int gid = (g << 8) + tid;
        int s2  = gid >> 7;
        int l4  = gid & 127;
        #pragma unroll
        for (int lv = 0; lv < 4; ++lv) {
            int l = (l4 << 2) + lv;
            uint4 p;
            p.x = cvt2((&xr[0].x)[lv], (&xr[1].x)[lv]);
            p.y = cvt2((&xr[2].x)[lv], (&xr[3].x)[lv]);
            p.z = cvt2((&xr[4].x)[lv], (&xr[5].x)[lv]);
            p.w = cvt2((&xr[6].x)[lv], (&xr[7].x)[lv]);
            *(uint4*)(xT + (s2 << 12) + (swz(l) << 3)) = p;
        }
    };

    // prologue: chunk 0
    loadg(0, 0, xr0);
    loadg(0, 1, xr1);
    storeg(0, xr0);
    storeg(1, xr1);
    __syncthreads();

    // ---- K loop: 8 chunks of 32 k, register-prefetch pipelined ----
    for (int kc = 0; kc < 8; ++kc) {
        if (kc < 7) loadg(kc + 1, 0, xr0);      // prefetch half the next chunk now

        bf16x8 av[4], bv[8];
        #pragma unroll
        for (int mt = 0; mt < 4; ++mt) {
            int sl = (kc << 2) + q;
            av[mt] = *(const bf16x8*)(wlds + (sl << 9) + ((swz((mt << 4) + m) ^ (sl & 7)) << 3));
        }
        #pragma unroll
        for (int nt = 0; nt < 8; ++nt)
            bv[nt] = *(const bf16x8*)(xT + (q << 12) + (swz((wv << 7) + (nt << 4) + m) << 3));

        #pragma unroll
        for (int mt = 0; mt < 4; ++mt)
            #pragma unroll
            for (int nt = 0; nt < 8; ++nt)
                acc[mt][nt] = __builtin_amdgcn_mfma_f32_16x16x32_bf16(av[mt], bv[nt], acc[mt][nt], 0, 0, 0);

        if (kc < 7) loadg(kc + 1, 1, xr1);      // other half: latency overlaps the barrier wait
        __syncthreads();                        // all waves done reading xT(kc)
        if (kc < 7) {
            storeg(0, xr0);
            storeg(1, xr1);
            __syncthreads();                    // xT(kc+1) visible
        }
    }
    // (last iteration's __syncthreads separates xT/wlds reads from the y2 alias below)

    // ---- epilogue ----
    int iv[8];
    #pragma unroll
    for (int nt = 0; nt < 8; ++nt)
        iv[nt] = idx[((size_t)b << 9) + (wv << 7) + (nt << 4) + m];

    // Y2 (acc mt=2,3) -> y2 bf16 transposed [col][row], b64 per (mt,nt)
    #pragma unroll
    for (int mt = 2; mt < 4; ++mt)
        #pragma unroll
        for (int nt = 0; nt < 8; ++nt) {
            int col  = (wv << 7) + (nt << 4) + m;
            int row0 = ((mt - 2) << 4) + (q << 2);     // D row = quad*4+reg (+16 per mt)
            uint2 p;
            p.x = cvt2(acc[mt][nt][0], acc[mt][nt][1]);
            p.y = cvt2(acc[mt][nt][2], acc[mt][nt][3]);
            *(uint2*)(y2 + col * 36 + row0) = p;
        }
    __syncthreads();

    // gather + per-row partial sums
    float vvl[2][8][4];
    float s_[2][4], q_[2][4];
    #pragma unroll
    for (int mt = 0; mt < 2; ++mt)
        #pragma unroll
        for (int r4 = 0; r4 < 4; ++r4) { s_[mt][r4] = 0.f; q_[mt][r4] = 0.f; }

    #pragma unroll
    for (int nt = 0; nt < 8; ++nt) {
        int  c   = iv[nt];
        bool inb = (c < 512);            // idx==512 -> pad column (zero)
        int  cc  = inb ? c : 0;
        #pragma unroll
        for (int mt = 0; mt < 2; ++mt) {
            uint2 g = *(const uint2*)(y2 + cc * 36 + (mt << 4) + (q << 2));
            float gv[4];
            gv[0] = inb ? bflo(g.x) : 0.f;
            gv[1] = inb ? bfhi(g.x) : 0.f;
            gv[2] = inb ? bflo(g.y) : 0.f;
            gv[3] = inb ? bfhi(g.y) : 0.f;
            #pragma unroll
            for (int r4 = 0; r4 < 4; ++r4) {
                float val = acc[mt][nt][r4] + gv[r4];   // Y1 + gathered Y2 (same o rows)
                vvl[mt][nt][r4] = val;
                s_[mt][r4] += val;
                q_[mt][r4] += val * val;
            }
        }
    }

    // reduce: 16-lane butterfly over m, cross-wave via red (no alias with y2)
    #pragma unroll
    for (int mt = 0; mt < 2; ++mt)
        #pragma unroll
        for (int r4 = 0; r4 < 4; ++r4) {
            float s = s_[mt][r4], ss = q_[mt][r4];
            #pragma unroll
            for (int off = 1; off < 16; off <<= 1) {
                s  += __shfl_xor(s,  off, 64);
                ss += __shfl_xor(ss, off, 64);
            }
            if (m == 0) {
                int r = (mt << 4) + (q << 2) + r4;
                red[(r << 3) + (wv << 1)]     = s;
                red[(r << 3) + (wv << 1) + 1] = ss;
            }
        }
    __syncthreads();

    // finalize: mean, biased var, rsqrt, relu, store
    #pragma unroll
    for (int mt = 0; mt < 2; ++mt)
        #pragma unroll
        for (int r4 = 0; r4 < 4; ++r4) {
            int r = (mt << 4) + (q << 2) + r4;
            float S = red[(r << 3)]     + red[(r << 3) + 2] + red[(r << 3) + 4] + red[(r << 3) + 6];
            float Q = red[(r << 3) + 1] + red[(r << 3) + 3] + red[(r << 3) + 5] + red[(r << 3) + 7];
            float mu  = S * (1.0f / 512.0f);
            float var = Q * (1.0f / 512.0f) - mu * mu;
            float rs  = rsqrtf(var + 1e-5f);
            float* op = out + (((size_t)(b << 8) + o0 + r) << 9) + (wv << 7) + m;
            #pragma unroll
            for (int nt = 0; nt < 8; ++nt) {
                float t = (vvl[mt][nt][r4] - mu) * rs;
                op[nt << 4] = fmaxf(t, 0.0f);
            }
        }
}

extern "C" void kernel_launch(void* const* d_in, const int* in_sizes, int n_in,
                              void* d_out, int out_size, void* d_ws, size_t ws_size,
                              hipStream_t stream) {
    const float* x   = (const float*)d_in[0];   // [256,256,512] fp32
    const int*   idx = (const int*)  d_in[1];   // [256,512] int32, 512 == pad
    const float* W   = (const float*)d_in[2];   // [256,512] fp32
    // d_in[3] (bias) unused: constant-over-L shift cancels in InstanceNorm.
    float* out = (float*)d_out;                 // [256,256,512] fp32

    edgeconv_fused<<<dim3(2048), dim3(256), 0, stream>>>(x, idx, W, out);
}

// Round 4
// 303.488 us; speedup vs baseline: 1.0736x; 1.0452x over previous
//
#include <hip/hip_runtime.h>
#include <hip/hip_bf16.h>
#include <stdint.h>

typedef __bf16 bf16x8 __attribute__((ext_vector_type(8)));
typedef float  f32x4  __attribute__((ext_vector_type(4)));

// packed fp32x2 -> bf16x2 (RNE) -- lowers to v_cvt_pk_bf16_f32 on gfx950
__device__ __forceinline__ uint32_t cvt2(float a, float b) {
    __hip_bfloat162 h = __float22bfloat162_rn(make_float2(a, b));
    uint32_t u; __builtin_memcpy(&u, &h, 4); return u;
}
__device__ __forceinline__ float bflo(uint32_t u) { uint32_t t = u << 16;         float f; __builtin_memcpy(&f, &t, 4); return f; }
__device__ __forceinline__ float bfhi(uint32_t u) { uint32_t t = u & 0xffff0000u; float f; __builtin_memcpy(&f, &t, 4); return f; }
__device__ __forceinline__ int swz(int u) { return u ^ ((u >> 3) & 7); }

// ============================================================================
// Kernel 1: pack x (and W) to bf16 in MFMA-fragment-ready transposed layouts.
//   xT[b][s][l][j] : k = s*8+j (s=0..31), l=0..511  -> B-frag = b128 at (b,s,col)
//   wT[og][s][r][j]: r<32 -> W1 row og*32+r, r>=32 -> W2 row og*32+r-32
// ============================================================================
__global__ __launch_bounds__(256, 4)
void pack_transpose(const float* __restrict__ x, const float* __restrict__ W,
                    unsigned short* __restrict__ xT, unsigned short* __restrict__ wT)
{
    const int tid = threadIdx.x;
    const int id  = blockIdx.x;
    if (id < 2048) {
        const int b = id >> 3, kc = id & 7;
        const int s2 = tid >> 6, l4 = tid & 63;          // slab-in-chunk, l-quad
        const float* src0 = x + ((size_t)b << 17) + ((size_t)((kc << 5) + (s2 << 3)) << 9);
        unsigned short* dst0 = xT + (((size_t)(b << 5) + (kc << 2) + s2) << 12);
        #pragma unroll
        for (int lh = 0; lh < 2; ++lh) {
            const int l0 = (lh << 8) + (l4 << 2);
            float4 xr[8];
            #pragma unroll
            for (int j = 0; j < 8; ++j)
                xr[j] = *(const float4*)(src0 + (j << 9) + l0);   // 1KB/instr coalesced
            #pragma unroll
            for (int lv = 0; lv < 4; ++lv) {
                uint4 p;
                p.x = cvt2((&xr[0].x)[lv], (&xr[1].x)[lv]);
                p.y = cvt2((&xr[2].x)[lv], (&xr[3].x)[lv]);
                p.z = cvt2((&xr[4].x)[lv], (&xr[5].x)[lv]);
                p.w = cvt2((&xr[6].x)[lv], (&xr[7].x)[lv]);
                *(uint4*)(dst0 + ((l0 + lv) << 3)) = p;  // 16B/lane, 64B stride; 4 instrs fill
            }
        }
    } else {
        const int og = id - 2048;
        const int r = tid & 63, sg = tid >> 6;
        const float* wrow = W + ((size_t)((og << 5) + (r & 31)) << 9) + ((r >> 5) << 8);
        #pragma unroll
        for (int ss = 0; ss < 8; ++ss) {
            const int s = (sg << 3) + ss;
            float4 f0 = *(const float4*)(wrow + (s << 3));
            float4 f1 = *(const float4*)(wrow + (s << 3) + 4);
            uint4 p;
            p.x = cvt2(f0.x, f0.y); p.y = cvt2(f0.z, f0.w);
            p.z = cvt2(f1.x, f1.y); p.w = cvt2(f1.z, f1.w);
            *(uint4*)(wT + (((((og << 5) + s) << 6) + r) << 3)) = p;
        }
    }
}

// ============================================================================
// Kernel 2: barrier-free GEMM. Block = (b, og): rows 0..31 = Y1, 32..63 = Y2,
// N=512, K=256. Frags load straight from global (L2/LLC-hot). LDS only for the
// epilogue gather. y = Y1 + gather_cols(Y2, idx); bias cancels; norm; ReLU.
// ============================================================================
__global__ __launch_bounds__(256, 2)
void edge_gemm(const unsigned short* __restrict__ xT,
               const unsigned short* __restrict__ wT,
               const int* __restrict__ idx,
               float* __restrict__ out)
{
    __shared__ __align__(16) unsigned char smem[37888];
    unsigned short* y2 = (unsigned short*)smem;          // bf16 [512 col][36]
    float* red         = (float*)(smem + 36864);         // fp32 [32 r][4 wv][2]

    const int tid  = threadIdx.x;
    const int wv   = tid >> 6;
    const int lane = tid & 63;
    const int m    = lane & 15;
    const int q    = lane >> 4;

    // XCD swizzle: 8 o-blocks of one b are 8 ids apart -> same XCD round-robin
    const int id  = blockIdx.x;
    const int rem = id & 63;
    const int b   = ((id >> 6) << 3) + (rem & 7);
    const int og  = rem >> 3;
    const int o0  = og << 5;

    const unsigned short* xb = xT + ((size_t)b << 17);   // b * 32*512*8
    const unsigned short* wb = wT + (og << 14);          // og * 32*64*8

    int iv[8];
    #pragma unroll
    for (int nt = 0; nt < 8; ++nt)
        iv[nt] = idx[((size_t)b << 9) + (wv << 7) + (nt << 4) + m];

    f32x4 acc[4][8];
    #pragma unroll
    for (int mt = 0; mt < 4; ++mt)
        #pragma unroll
        for (int nt = 0; nt < 8; ++nt)
            acc[mt][nt] = (f32x4){0.f, 0.f, 0.f, 0.f};

    // ---- K loop: no LDS, no barriers; compiler pipelines 96 b128 loads ----
    #pragma unroll
    for (int kc = 0; kc < 8; ++kc) {
        const int s = (kc << 2) + q;
        bf16x8 av[4], bv[8];
        const unsigned short* ab = wb + (s << 9) + (m << 3);
        #pragma unroll
        for (int mt = 0; mt < 4; ++mt)
            av[mt] = *(const bf16x8*)(ab + (mt << 7));   // A[mt*16+m][k=s*8+j]
        const unsigned short* bb = xb + (s << 12) + (((wv << 7) + m) << 3);
        #pragma unroll
        for (int nt = 0; nt < 8; ++nt)
            bv[nt] = *(const bf16x8*)(bb + (nt << 7));   // B[k=s*8+j][wv*128+nt*16+m]
        #pragma unroll
        for (int mt = 0; mt < 4; ++mt)
            #pragma unroll
            for (int nt = 0; nt < 8; ++nt)
                acc[mt][nt] = __builtin_amdgcn_mfma_f32_16x16x32_bf16(av[mt], bv[nt], acc[mt][nt], 0, 0, 0);
    }

    // ---- epilogue: Y2 -> LDS (bf16, transposed [col][row]) ----
    #pragma unroll
    for (int mt = 2; mt < 4; ++mt)
        #pragma unroll
        for (int nt = 0; nt < 8; ++nt) {
            int col  = (wv << 7) + (nt << 4) + m;
            int row0 = ((mt - 2) << 4) + (q << 2);
            uint2 p;
            p.x = cvt2(acc[mt][nt][0], acc[mt][nt][1]);
            p.y = cvt2(acc[mt][nt][2], acc[mt][nt][3]);
            *(uint2*)(y2 + col * 36 + row0) = p;
        }
    __syncthreads();

    float vvl[2][8][4];
    float s_[2][4], q_[2][4];
    #pragma unroll
    for (int mt = 0; mt < 2; ++mt)
        #pragma unroll
        for (int r4 = 0; r4 < 4; ++r4) { s_[mt][r4] = 0.f; q_[mt][r4] = 0.f; }

    #pragma unroll
    for (int nt = 0; nt < 8; ++nt) {
        int  c   = iv[nt];
        bool inb = (c < 512);                    // idx==512 -> pad column (zero)
        int  cc  = inb ? c : 0;
        #pragma unroll
        for (int mt = 0; mt < 2; ++mt) {
            uint2 g = *(const uint2*)(y2 + cc * 36 + (mt << 4) + (q << 2));
            float gv[4];
            gv[0] = inb ? bflo(g.x) : 0.f;
            gv[1] = inb ? bfhi(g.x) : 0.f;
            gv[2] = inb ? bflo(g.y) : 0.f;
            gv[3] = inb ? bfhi(g.y) : 0.f;
            #pragma unroll
            for (int r4 = 0; r4 < 4; ++r4) {
                float val = acc[mt][nt][r4] + gv[r4];
                vvl[mt][nt][r4] = val;
                s_[mt][r4] += val;
                q_[mt][r4] += val * val;
            }
        }
    }

    // reduce: 16-lane butterfly over m, cross-wave via red (separate region)
    #pragma unroll
    for (int mt = 0; mt < 2; ++mt)
        #pragma unroll
        for (int r4 = 0; r4 < 4; ++r4) {
            float s = s_[mt][r4], ss = q_[mt][r4];
            #pragma unroll
            for (int off = 1; off < 16; off <<= 1) {
                s  += __shfl_xor(s,  off, 64);
                ss += __shfl_xor(ss, off, 64);
            }
            if (m == 0) {
                int r = (mt << 4) + (q << 2) + r4;
                red[(r << 3) + (wv << 1)]     = s;
                red[(r << 3) + (wv << 1) + 1] = ss;
            }
        }
    __syncthreads();

    #pragma unroll
    for (int mt = 0; mt < 2; ++mt)
        #pragma unroll
        for (int r4 = 0; r4 < 4; ++r4) {
            int r = (mt << 4) + (q << 2) + r4;
            float S = red[(r << 3)]     + red[(r << 3) + 2] + red[(r << 3) + 4] + red[(r << 3) + 6];
            float Q = red[(r << 3) + 1] + red[(r << 3) + 3] + red[(r << 3) + 5] + red[(r << 3) + 7];
            float mu  = S * (1.0f / 512.0f);
            float var = Q * (1.0f / 512.0f) - mu * mu;
            float rs  = rsqrtf(var + 1e-5f);
            float* op = out + (((size_t)(b << 8) + o0 + r) << 9) + (wv << 7) + m;
            #pragma unroll
            for (int nt = 0; nt < 8; ++nt) {
                float t = (vvl[mt][nt][r4] - mu) * rs;
                op[nt << 4] = fmaxf(t, 0.0f);
            }
        }
}

// ============================================================================
// Fallback (ws too small): round-2 fused single kernel, unchanged.
// ============================================================================
__global__ __launch_bounds__(256, 2)
void edgeconv_fused(const float* __restrict__ x,
                    const int*   __restrict__ idx,
                    const float* __restrict__ W,
                    float*       __restrict__ out)
{
    __shared__ __align__(16) unsigned char smem[65536];
    unsigned short* wlds = (unsigned short*)smem;
    unsigned short* xT   = (unsigned short*)(smem + 32768);
    unsigned short* y2   = (unsigned short*)smem;
    float*          red  = (float*)(smem + 38912);

    const int tid  = threadIdx.x;
    const int wv   = tid >> 6;
    const int lane = tid & 63;
    const int m    = lane & 15;
    const int q    = lane >> 4;

    const int id  = blockIdx.x;
    const int rem = id & 63;
    const int b   = ((id >> 6) << 3) + (rem & 7);
    const int o0  = (rem >> 3) << 5;

    const float* xb = x + ((size_t)b << 17);

    #pragma unroll
    for (int i = 0; i < 16; ++i) {
        int r = (i << 2) + wv;
        const float4 f = *(const float4*)(W + ((size_t)(o0 + (r & 31)) << 9)
                                            + ((r >> 5) << 8) + (lane << 2));
        uint2 p; p.x = cvt2(f.x, f.y); p.y = cvt2(f.z, f.w);
        int sl = lane >> 1;
        *(uint2*)(wlds + (sl << 9) + ((swz(r) ^ (sl & 7)) << 3) + ((lane & 1) << 2)) = p;
    }

    f32x4 acc[4][8];
    #pragma unroll
    for (int mt = 0; mt < 4; ++mt)
        #pragma unroll
        for (int nt = 0; nt < 8; ++nt)
            acc[mt][nt] = (f32x4){0.f, 0.f, 0.f, 0.f};

    float4 xr0[8], xr1[8];
    auto loadg = [&](int kc, int g, float4* xr) {
        int gid = (g << 8) + tid;
        int s2  = gid >> 7;
        int l4  = gid & 127;
        const float* base = xb + ((size_t)((kc << 5) + (s2 << 3)) << 9) + (l4 << 2);
        #pragma unroll
        for (int j = 0; j < 8; ++j) xr[j] = *(const float4*)(base + (j << 9));
    };
    auto storeg = [&](int g, const float4* xr) {
        int gid = (g << 8) + tid;
        int s2  = gid >> 7;
        int l4  = gid & 127;
        #pragma unroll
        for (int lv = 0; lv < 4; ++lv) {
            int l = (l4 << 2) + lv;
            uint4 p;
            p.x = cvt2((&xr[0].x)[lv], (&xr[1].x)[lv]);
            p.y = cvt2((&xr[2].x)[lv], (&xr[3].x)[lv]);
            p.z = cvt2((&xr[4].x)[lv], (&xr[5].x)[lv]);
            p.w = cvt2((&xr[6].x)[lv], (&xr[7].x)[lv]);
            *(uint4*)(xT + (s2 << 12) + (swz(l) << 3)) = p;
        }
    };

    loadg(0, 0, xr0);
    loadg(0, 1, xr1);
    storeg(0, xr0);
    storeg(1, xr1);
    __syncthreads();

    for (int kc = 0; kc < 8; ++kc) {
        if (kc < 7) loadg(kc + 1, 0, xr0);

        bf16x8 av[4], bv[8];
        #pragma unroll
        for (int mt = 0; mt < 4; ++mt) {
            int sl = (kc << 2) + q;
            av[mt] = *(const bf16x8*)(wlds + (sl << 9) + ((swz((mt << 4) + m) ^ (sl & 7)) << 3));
        }
        #pragma unroll
        for (int nt = 0; nt < 8; ++nt)
            bv[nt] = *(const bf16x8*)(xT + (q << 12) + (swz((wv << 7) + (nt << 4) + m) << 3));

        #pragma unroll
        for (int mt = 0; mt < 4; ++mt)
            #pragma unroll
            for (int nt = 0; nt < 8; ++nt)
                acc[mt][nt] = __builtin_amdgcn_mfma_f32_16x16x32_bf16(av[mt], bv[nt], acc[mt][nt], 0, 0, 0);

        if (kc < 7) loadg(kc + 1, 1, xr1);
        __syncthreads();
        if (kc < 7) {
            storeg(0, xr0);
            storeg(1, xr1);
            __syncthreads();
        }
    }

    int iv[8];
    #pragma unroll
    for (int nt = 0; nt < 8; ++nt)
        iv[nt] = idx[((size_t)b << 9) + (wv << 7) + (nt << 4) + m];

    #pragma unroll
    for (int mt = 2; mt < 4; ++mt)
        #pragma unroll
        for (int nt = 0; nt < 8; ++nt) {
            int col  = (wv << 7) + (nt << 4) + m;
            int row0 = ((mt - 2) << 4) + (q << 2);
            uint2 p;
            p.x = cvt2(acc[mt][nt][0], acc[mt][nt][1]);
            p.y = cvt2(acc[mt][nt][2], acc[mt][nt][3]);
            *(uint2*)(y2 + col * 36 + row0) = p;
        }
    __syncthreads();

    float vvl[2][8][4];
    float s_[2][4], q_[2][4];
    #pragma unroll
    for (int mt = 0; mt < 2; ++mt)
        #pragma unroll
        for (int r4 = 0; r4 < 4; ++r4) { s_[mt][r4] = 0.f; q_[mt][r4] = 0.f; }

    #pragma unroll
    for (int nt = 0; nt < 8; ++nt) {
        int  c   = iv[nt];
        bool inb = (c < 512);
        int  cc  = inb ? c : 0;
        #pragma unroll
        for (int mt = 0; mt < 2; ++mt) {
            uint2 g = *(const uint2*)(y2 + cc * 36 + (mt << 4) + (q << 2));
            float gv[4];
            gv[0] = inb ? bflo(g.x) : 0.f;
            gv[1] = inb ? bfhi(g.x) : 0.f;
            gv[2] = inb ? bflo(g.y) : 0.f;
            gv[3] = inb ? bfhi(g.y) : 0.f;
            #pragma unroll
            for (int r4 = 0; r4 < 4; ++r4) {
                float val = acc[mt][nt][r4] + gv[r4];
                vvl[mt][nt][r4] = val;
                s_[mt][r4] += val;
                q_[mt][r4] += val * val;
            }
        }
    }

    #pragma unroll
    for (int mt = 0; mt < 2; ++mt)
        #pragma unroll
        for (int r4 = 0; r4 < 4; ++r4) {
            float s = s_[mt][r4], ss = q_[mt][r4];
            #pragma unroll
            for (int off = 1; off < 16; off <<= 1) {
                s  += __shfl_xor(s,  off, 64);
                ss += __shfl_xor(ss, off, 64);
            }
            if (m == 0) {
                int r = (mt << 4) + (q << 2) + r4;
                red[(r << 3) + (wv << 1)]     = s;
                red[(r << 3) + (wv << 1) + 1] = ss;
            }
        }
    __syncthreads();

    #pragma unroll
    for (int mt = 0; mt < 2; ++mt)
        #pragma unroll
        for (int r4 = 0; r4 < 4; ++r4) {
            int r = (mt << 4) + (q << 2) + r4;
            float S = red[(r << 3)]     + red[(r << 3) + 2] + red[(r << 3) + 4] + red[(r << 3) + 6];
            float Q = red[(r << 3) + 1] + red[(r << 3) + 3] + red[(r << 3) + 5] + red[(r << 3) + 7];
            float mu  = S * (1.0f / 512.0f);
            float var = Q * (1.0f / 512.0f) - mu * mu;
            float rs  = rsqrtf(var + 1e-5f);
            float* op = out + (((size_t)(b << 8) + o0 + r) << 9) + (wv << 7) + m;
            #pragma unroll
            for (int nt = 0; nt < 8; ++nt) {
                float t = (vvl[mt][nt][r4] - mu) * rs;
                op[nt << 4] = fmaxf(t, 0.0f);
            }
        }
}

extern "C" void kernel_launch(void* const* d_in, const int* in_sizes, int n_in,
                              void* d_out, int out_size, void* d_ws, size_t ws_size,
                              hipStream_t stream) {
    const float* x   = (const float*)d_in[0];   // [256,256,512] fp32
    const int*   idx = (const int*)  d_in[1];   // [256,512] int32, 512 == pad
    const float* W   = (const float*)d_in[2];   // [256,512] fp32
    // d_in[3] (bias) unused: constant-over-L shift cancels in InstanceNorm.
    float* out = (float*)d_out;                 // [256,256,512] fp32

    const size_t xT_bytes = (size_t)256 * 32 * 512 * 8 * 2;   // 67,108,864
    const size_t wT_bytes = (size_t)8 * 32 * 64 * 8 * 2;      // 262,144

    if (ws_size >= xT_bytes + wT_bytes) {
        unsigned short* xT = (unsigned short*)d_ws;
        unsigned short* wT = (unsigned short*)((char*)d_ws + xT_bytes);
        pack_transpose<<<dim3(2056), dim3(256), 0, stream>>>(x, W, xT, wT);
        edge_gemm<<<dim3(2048), dim3(256), 0, stream>>>(xT, wT, idx, out);
    } else {
        edgeconv_fused<<<dim3(2048), dim3(256), 0, stream>>>(x, idx, W, out);
    }
}